// Round 1
// baseline (88.525 us; speedup 1.0000x reference)
//
#include <hip/hip_runtime.h>
#include <math.h>

// Model: tiny transformer, B=32,S=1024,L=2,E=4,H=2,D=2,FFN=16,V=8.
// Key insight: non-causal attention + V=8 vocab => x[b,s] is a pure function
// of (b, tok[b,s]) at every stage (softmax over repeated keys == histogram-
// weighted softmax over the 8 distinct key values). Exact collapse:
//   per batch: histogram[8] -> run transformer on 8 virtual tokens -> 8x8
//   logits table -> scatter table[tok[b,s]] into out[b,s,:].

#define Bz  32
#define Sz  1024
#define Lz  2
#define Ez  4
#define Hz  2
#define Dz  2
#define FFNz 16
#define Vz  8
#define EPSz 1e-5f

#define CHUNKS 8                 // blocks per batch
#define POSPC (Sz / CHUNKS)      // 128 positions per block
#define NT 256

__device__ __forceinline__ void layernorm4(const float* x, const float* g,
                                           const float* b, float* h) {
    float mu = 0.25f * (x[0] + x[1] + x[2] + x[3]);
    float d0 = x[0] - mu, d1 = x[1] - mu, d2 = x[2] - mu, d3 = x[3] - mu;
    float var = 0.25f * (d0 * d0 + d1 * d1 + d2 * d2 + d3 * d3);
    float r = 1.0f / sqrtf(var + EPSz);
    h[0] = d0 * r * g[0] + b[0];
    h[1] = d1 * r * g[1] + b[1];
    h[2] = d2 * r * g[2] + b[2];
    h[3] = d3 * r * g[3] + b[3];
}

__global__ __launch_bounds__(NT) void tformer_collapse(
    const int* __restrict__ tok,
    const float* __restrict__ emb,
    const float* __restrict__ ln1_g, const float* __restrict__ ln1_b,
    const float* __restrict__ wqkv, const float* __restrict__ wo,
    const float* __restrict__ ln2_g, const float* __restrict__ ln2_b,
    const float* __restrict__ w1, const float* __restrict__ b1,
    const float* __restrict__ w2, const float* __restrict__ b2,
    const float* __restrict__ out_w,
    float* __restrict__ out)
{
    __shared__ int   toks[Sz];
    __shared__ int   hist[Vz];
    __shared__ float kv_k[Vz][Ez];
    __shared__ float kv_v[Vz][Ez];
    __shared__ __align__(16) float table[Vz][Vz];

    const int b     = blockIdx.x / CHUNKS;
    const int chunk = blockIdx.x % CHUNKS;
    const int tid   = threadIdx.x;

    if (tid < Vz) hist[tid] = 0;
    __syncthreads();

    // --- load this batch's tokens + LDS histogram (coalesced) ---
    const int* tb = tok + b * Sz;
    #pragma unroll
    for (int k = 0; k < Sz / NT; ++k) {
        int t = tb[tid + k * NT];
        toks[tid + k * NT] = t;
        atomicAdd(&hist[t], 1);
    }
    __syncthreads();

    // --- 8 threads run the transformer on the 8 virtual tokens ---
    float x[Ez];
    float cnt[Vz];
    const int t = tid;  // virtual token id for tid < Vz
    if (tid < Vz) {
        #pragma unroll
        for (int e = 0; e < Ez; ++e) x[e] = emb[t * Ez + e];
        #pragma unroll
        for (int j = 0; j < Vz; ++j) cnt[j] = (float)hist[j];
    }

    #pragma unroll
    for (int l = 0; l < Lz; ++l) {
        float q[Ez];
        if (tid < Vz) {
            // LN1
            float h[Ez];
            layernorm4(x, ln1_g + l * Ez, ln1_b + l * Ez, h);
            // qkv = wqkv[l] @ h   (wqkv row-major [3E][E])
            const float* wq = wqkv + l * 3 * Ez * Ez;
            #pragma unroll
            for (int f = 0; f < Ez; ++f) {
                float sq = 0.f, sk = 0.f, sv = 0.f;
                #pragma unroll
                for (int e = 0; e < Ez; ++e) {
                    sq += wq[f * Ez + e] * h[e];
                    sk += wq[(Ez + f) * Ez + e] * h[e];
                    sv += wq[(2 * Ez + f) * Ez + e] * h[e];
                }
                q[f] = sq;
                kv_k[t][f] = sk;
                kv_v[t][f] = sv;
            }
        }
        __syncthreads();   // publish k,v for all 8 virtual tokens

        if (tid < Vz) {
            // histogram-weighted attention over the 8 distinct keys
            float o[Ez];
            #pragma unroll
            for (int hh = 0; hh < Hz; ++hh) {
                float sc[Vz];
                float m = -1e30f;
                #pragma unroll
                for (int j = 0; j < Vz; ++j) {
                    float s = 0.f;
                    #pragma unroll
                    for (int d = 0; d < Dz; ++d)
                        s += q[hh * Dz + d] * kv_k[j][hh * Dz + d];
                    s *= 0.70710678118654752f;   // 1/sqrt(D), D=2
                    sc[j] = s;
                    m = fmaxf(m, s);
                }
                float Z = 0.f;
                float acc0 = 0.f, acc1 = 0.f;
                #pragma unroll
                for (int j = 0; j < Vz; ++j) {
                    float w = cnt[j] * expf(sc[j] - m);
                    Z += w;
                    acc0 += w * kv_v[j][hh * Dz + 0];
                    acc1 += w * kv_v[j][hh * Dz + 1];
                }
                o[hh * Dz + 0] = acc0 / Z;
                o[hh * Dz + 1] = acc1 / Z;
            }
            // x += wo[l] @ o
            #pragma unroll
            for (int f = 0; f < Ez; ++f) {
                float s = 0.f;
                #pragma unroll
                for (int e = 0; e < Ez; ++e)
                    s += o[e] * wo[(l * Ez + f) * Ez + e];
                x[f] += s;
            }
            // FFN sublayer
            float h2[Ez];
            layernorm4(x, ln2_g + l * Ez, ln2_b + l * Ez, h2);
            float a0 = 0.f, a1 = 0.f, a2 = 0.f, a3 = 0.f;
            #pragma unroll
            for (int f = 0; f < FFNz; ++f) {
                float u = b1[l * FFNz + f];
                #pragma unroll
                for (int e = 0; e < Ez; ++e)
                    u += w1[(l * FFNz + f) * Ez + e] * h2[e];
                // exact GELU: 0.5*u*(1+erf(u/sqrt(2)))
                float g = 0.5f * u * (1.0f + erff(u * 0.70710678118654752f));
                a0 += g * w2[(l * Ez + 0) * FFNz + f];
                a1 += g * w2[(l * Ez + 1) * FFNz + f];
                a2 += g * w2[(l * Ez + 2) * FFNz + f];
                a3 += g * w2[(l * Ez + 3) * FFNz + f];
            }
            x[0] += a0 + b2[l * Ez + 0];
            x[1] += a1 + b2[l * Ez + 1];
            x[2] += a2 + b2[l * Ez + 2];
            x[3] += a3 + b2[l * Ez + 3];
        }
        __syncthreads();   // protect kv_k/kv_v before next layer overwrites
    }

    // --- logits table ---
    if (tid < Vz) {
        #pragma unroll
        for (int vv = 0; vv < Vz; ++vv) {
            float s = 0.f;
            #pragma unroll
            for (int e = 0; e < Ez; ++e) s += x[e] * out_w[vv * Ez + e];
            table[t][vv] = s;
        }
    }
    __syncthreads();

    // --- scatter: 128 positions x 8 floats = 256 float4 stores (coalesced) ---
    const int posBase = chunk * POSPC;
    const int p    = tid >> 1;      // 0..127
    const int part = tid & 1;       // which float4 of the 8-float row
    const int tk   = toks[posBase + p];
    float4 val = ((const float4*)&table[tk][0])[part];
    float4* out4 = (float4*)(out + ((size_t)b * Sz + posBase) * Vz);
    out4[tid] = val;
}

extern "C" void kernel_launch(void* const* d_in, const int* in_sizes, int n_in,
                              void* d_out, int out_size, void* d_ws, size_t ws_size,
                              hipStream_t stream) {
    const int*   tok   = (const int*)  d_in[0];
    const float* emb   = (const float*)d_in[1];
    const float* ln1_g = (const float*)d_in[2];
    const float* ln1_b = (const float*)d_in[3];
    const float* wqkv  = (const float*)d_in[4];
    const float* wo    = (const float*)d_in[5];
    const float* ln2_g = (const float*)d_in[6];
    const float* ln2_b = (const float*)d_in[7];
    const float* w1    = (const float*)d_in[8];
    const float* b1    = (const float*)d_in[9];
    const float* w2    = (const float*)d_in[10];
    const float* b2    = (const float*)d_in[11];
    const float* out_w = (const float*)d_in[12];
    float* out = (float*)d_out;

    dim3 grid(Bz * CHUNKS);   // 256 blocks -> one per CU
    dim3 block(NT);
    tformer_collapse<<<grid, block, 0, stream>>>(
        tok, emb, ln1_g, ln1_b, wqkv, wo, ln2_g, ln2_b,
        w1, b1, w2, b2, out_w, out);
}